// Round 3
// baseline (682.100 us; speedup 1.0000x reference)
//
#include <hip/hip_runtime.h>

#define M_DIM 8192
#define K_DIM 2048
#define N_DIM 5632

typedef __attribute__((ext_vector_type(8))) short short8;
typedef __attribute__((ext_vector_type(4))) float f32x4;

// fp32 -> bf16 round-to-nearest-even (bit trick; inputs are finite)
__device__ __forceinline__ short f2b(float f) {
  union { float f; unsigned u; } v; v.f = f;
  unsigned r = v.u + 0x7FFFu + ((v.u >> 16) & 1u);
  return (short)(r >> 16);
}

// async global->LDS, 16B per lane. LDS dest must be wave-uniform base + lane*16.
__device__ __forceinline__ void async16(void* lds, const void* g) {
  __builtin_amdgcn_global_load_lds(
      (const __attribute__((address_space(1))) unsigned*)g,
      (__attribute__((address_space(3))) unsigned*)lds,
      16, 0, 0);
}

// ---------------- Kernel 1: fused prep --------------------------------------
// blocks [0, 8192): x fp32 -> bf16 (8 elems/thread)
// blocks [8192, 8192+5632): dequant int4 + fold rank-16 LoRA into W' (bf16)
//   W'[o][i] = (q - zero[g]) * scale[g] + 2 * sum_r A[i][r] * B[r][o]
#define CVT_BLOCKS 8192
__global__ __launch_bounds__(256) void prep_kernel(
    const float* __restrict__ x, const int* __restrict__ packed,
    const float* __restrict__ scales, const float* __restrict__ zeros,
    const float* __restrict__ lA, const float* __restrict__ lB,
    short* __restrict__ xb, short* __restrict__ wb) {
  if (blockIdx.x < CVT_BLOCKS) {
    long t = (long)blockIdx.x * 256 + threadIdx.x;   // 8 elements per thread
    const float4* xv = (const float4*)x;
    float4 f0 = xv[2 * t];
    float4 f1 = xv[2 * t + 1];
    short8 o;
    o[0] = f2b(f0.x); o[1] = f2b(f0.y); o[2] = f2b(f0.z); o[3] = f2b(f0.w);
    o[4] = f2b(f1.x); o[5] = f2b(f1.y); o[6] = f2b(f1.z); o[7] = f2b(f1.w);
    *(short8*)(xb + 8 * t) = o;
    return;
  }
  int o = blockIdx.x - CVT_BLOCKS;
  int i0 = threadIdx.x * 8;                  // first of 8 W elements in row o
  long e0 = (long)o * K_DIM + i0;            // flat W index
  int4 p = ((const int4*)packed)[e0 >> 3];   // 4 packed bytes -> 8 codes
  int g = (int)(e0 >> 7);                    // group of 128
  float s = scales[g], z = zeros[g];

  float bcol[16];                            // B column, pre-scaled by lora 2.0
#pragma unroll
  for (int r = 0; r < 16; ++r) bcol[r] = lB[r * N_DIM + o] * 2.0f;

  short8 out8;
#pragma unroll
  for (int d = 0; d < 4; ++d) {
    int pv = (&p.x)[d];                      // two nibbles
    float w0 = ((float)(pv & 0xF) - z) * s;
    float w1 = ((float)((pv >> 4) & 0xF) - z) * s;
    const float4* a0 = (const float4*)&lA[(i0 + 2 * d) * 16];
    const float4* a1 = (const float4*)&lA[(i0 + 2 * d + 1) * 16];
    float acc0 = 0.f, acc1 = 0.f;
#pragma unroll
    for (int r4 = 0; r4 < 4; ++r4) {
      float4 av0 = a0[r4], av1 = a1[r4];
      acc0 += av0.x * bcol[4 * r4] + av0.y * bcol[4 * r4 + 1] +
              av0.z * bcol[4 * r4 + 2] + av0.w * bcol[4 * r4 + 3];
      acc1 += av1.x * bcol[4 * r4] + av1.y * bcol[4 * r4 + 1] +
              av1.z * bcol[4 * r4 + 2] + av1.w * bcol[4 * r4 + 3];
    }
    out8[2 * d] = f2b(w0 + acc0);
    out8[2 * d + 1] = f2b(w1 + acc1);
  }
  *(short8*)(wb + e0) = out8;
}

// ---------------- Kernel 2: C[m][n] = sum_k X[m][k] * W'[n][k] ---------------
// Block tile 128x256, BK=64, 4 waves in 2x2, each wave 64x128 (4x8 16x16x32
// frags). LDS fragment traffic per output is 0.75x the 64x64-wave version.
// XOR swizzle: chunk c of row r lives at slot (c ^ (r&7)) -> 0 bank conflicts.
__global__ __launch_bounds__(256) void gemm_kernel(const short* __restrict__ xb,
                                                   const short* __restrict__ wb,
                                                   float* __restrict__ out) {
  __shared__ __align__(16) short As[128 * 64];  // 16 KB
  __shared__ __align__(16) short Bs[256 * 64];  // 32 KB

  const int tid = threadIdx.x;
  const int wave = tid >> 6, lane = tid & 63;
  const int wm = wave >> 1, wn = wave & 1;      // 2x2 wave grid; wave = 64x128
  const int l15 = lane & 15, quad = lane >> 4;
  const int m0 = blockIdx.y * 128, n0 = blockIdx.x * 256;
  const short* a_base = xb + (size_t)m0 * K_DIM;
  const short* b_base = wb + (size_t)n0 * K_DIM;

  f32x4 acc[4][8] = {};

  // Swizzled, k0-invariant LDS read offsets (shorts).
  int a_off[2][4], b_off[2][8];
#pragma unroll
  for (int ks = 0; ks < 2; ++ks) {
    int c = ks * 4 + quad;                       // chunk index 0..7
#pragma unroll
    for (int i = 0; i < 4; ++i) {
      int ra = wm * 64 + i * 16 + l15;
      a_off[ks][i] = (ra * 8 + (c ^ (ra & 7))) * 8;
    }
#pragma unroll
    for (int i = 0; i < 8; ++i) {
      int rb = wn * 128 + i * 16 + l15;
      b_off[ks][i] = (rb * 8 + (c ^ (rb & 7))) * 8;
    }
  }

  for (int k0 = 0; k0 < K_DIM; k0 += 64) {
    __syncthreads();  // previous tile's LDS reads done before overwrite
#pragma unroll
    for (int it = 0; it < 4; ++it) {            // A: 1024 chunks
      int gi = it * 256 + tid;
      int row = gi >> 3;                        // 0..127
      int c = (gi & 7) ^ (row & 7);
      async16(&As[gi * 8], a_base + (size_t)row * K_DIM + k0 + c * 8);
    }
#pragma unroll
    for (int it = 0; it < 8; ++it) {            // B: 2048 chunks
      int gi = it * 256 + tid;
      int row = gi >> 3;                        // 0..255
      int c = (gi & 7) ^ (row & 7);
      async16(&Bs[gi * 8], b_base + (size_t)row * K_DIM + k0 + c * 8);
    }
    __syncthreads();  // vmcnt(0) drain -> LDS ready

#pragma unroll
    for (int ks = 0; ks < 2; ++ks) {
      short8 af[4], bf[8];
#pragma unroll
      for (int mi = 0; mi < 4; ++mi) af[mi] = *(const short8*)&As[a_off[ks][mi]];
#pragma unroll
      for (int ni = 0; ni < 8; ++ni) bf[ni] = *(const short8*)&Bs[b_off[ks][ni]];
#pragma unroll
      for (int mi = 0; mi < 4; ++mi)
#pragma unroll
        for (int ni = 0; ni < 8; ++ni)
          acc[mi][ni] = __builtin_amdgcn_mfma_f32_16x16x32_bf16(
              af[mi], bf[ni], acc[mi][ni], 0, 0, 0);
    }
  }

  // Epilogue: C/D layout col = lane&15, row = quad*4 + reg  [m89-verified]
  float* op = out + (size_t)(m0 + wm * 64 + quad * 4) * N_DIM + n0 + wn * 128 + l15;
#pragma unroll
  for (int mi = 0; mi < 4; ++mi)
#pragma unroll
    for (int r = 0; r < 4; ++r)
#pragma unroll
      for (int ni = 0; ni < 8; ++ni)
        op[(size_t)(mi * 16 + r) * N_DIM + ni * 16] = acc[mi][ni][r];
}

// -----------------------------------------------------------------------------
extern "C" void kernel_launch(void* const* d_in, const int* in_sizes, int n_in,
                              void* d_out, int out_size, void* d_ws, size_t ws_size,
                              hipStream_t stream) {
  const float* x      = (const float*)d_in[0];  // [4,2048,2048] fp32
  const int*   packed = (const int*)d_in[1];    // [5767168] int32 (byte values)
  const float* scales = (const float*)d_in[2];  // [90112]
  const float* zeros  = (const float*)d_in[3];  // [90112]
  const float* lA     = (const float*)d_in[4];  // [2048,16]
  const float* lB     = (const float*)d_in[5];  // [16,5632]
  float* out = (float*)d_out;                   // [4,2048,5632] fp32

  short* xb = (short*)d_ws;                     // x in bf16: 16,777,216 shorts
  short* wb = xb + (size_t)M_DIM * K_DIM;       // W' in bf16: 11,534,336 shorts

  prep_kernel<<<CVT_BLOCKS + N_DIM, 256, 0, stream>>>(x, packed, scales, zeros,
                                                      lA, lB, xb, wb);
  gemm_kernel<<<dim3(N_DIM / 256, M_DIM / 128), 256, 0, stream>>>(xb, wb, out);
}

// Round 4
// 577.447 us; speedup vs baseline: 1.1812x; 1.1812x over previous
//
#include <hip/hip_runtime.h>

#define M_DIM 8192
#define K_DIM 2048
#define N_DIM 5632

typedef __attribute__((ext_vector_type(8))) short short8;
typedef __attribute__((ext_vector_type(4))) float f32x4;

// fp32 -> bf16 round-to-nearest-even (bit trick; inputs are finite)
__device__ __forceinline__ short f2b(float f) {
  union { float f; unsigned u; } v; v.f = f;
  unsigned r = v.u + 0x7FFFu + ((v.u >> 16) & 1u);
  return (short)(r >> 16);
}

// async global->LDS, 16B per lane. LDS dest must be wave-uniform base + lane*16.
__device__ __forceinline__ void async16(void* lds, const void* g) {
  __builtin_amdgcn_global_load_lds(
      (const __attribute__((address_space(1))) unsigned*)g,
      (__attribute__((address_space(3))) unsigned*)lds,
      16, 0, 0);
}

// ---------------- Kernel 1: fused prep --------------------------------------
// blocks [0, 8192): x fp32 -> bf16 (8 elems/thread)
// blocks [8192, 8192+5632): dequant int4 + fold rank-16 LoRA into W' (bf16)
//   W'[o][i] = (q - zero[g]) * scale[g] + 2 * sum_r A[i][r] * B[r][o]
#define CVT_BLOCKS 8192
__global__ __launch_bounds__(256) void prep_kernel(
    const float* __restrict__ x, const int* __restrict__ packed,
    const float* __restrict__ scales, const float* __restrict__ zeros,
    const float* __restrict__ lA, const float* __restrict__ lB,
    short* __restrict__ xb, short* __restrict__ wb) {
  if (blockIdx.x < CVT_BLOCKS) {
    long t = (long)blockIdx.x * 256 + threadIdx.x;   // 8 elements per thread
    const float4* xv = (const float4*)x;
    float4 f0 = xv[2 * t];
    float4 f1 = xv[2 * t + 1];
    short8 o;
    o[0] = f2b(f0.x); o[1] = f2b(f0.y); o[2] = f2b(f0.z); o[3] = f2b(f0.w);
    o[4] = f2b(f1.x); o[5] = f2b(f1.y); o[6] = f2b(f1.z); o[7] = f2b(f1.w);
    *(short8*)(xb + 8 * t) = o;
    return;
  }
  int o = blockIdx.x - CVT_BLOCKS;
  int i0 = threadIdx.x * 8;                  // first of 8 W elements in row o
  long e0 = (long)o * K_DIM + i0;            // flat W index
  int4 p = ((const int4*)packed)[e0 >> 3];   // 4 packed bytes -> 8 codes
  int g = (int)(e0 >> 7);                    // group of 128
  float s = scales[g], z = zeros[g];

  float bcol[16];                            // B column, pre-scaled by lora 2.0
#pragma unroll
  for (int r = 0; r < 16; ++r) bcol[r] = lB[r * N_DIM + o] * 2.0f;

  short8 out8;
#pragma unroll
  for (int d = 0; d < 4; ++d) {
    int pv = (&p.x)[d];                      // two nibbles
    float w0 = ((float)(pv & 0xF) - z) * s;
    float w1 = ((float)((pv >> 4) & 0xF) - z) * s;
    const float4* a0 = (const float4*)&lA[(i0 + 2 * d) * 16];
    const float4* a1 = (const float4*)&lA[(i0 + 2 * d + 1) * 16];
    float acc0 = 0.f, acc1 = 0.f;
#pragma unroll
    for (int r4 = 0; r4 < 4; ++r4) {
      float4 av0 = a0[r4], av1 = a1[r4];
      acc0 += av0.x * bcol[4 * r4] + av0.y * bcol[4 * r4 + 1] +
              av0.z * bcol[4 * r4 + 2] + av0.w * bcol[4 * r4 + 3];
      acc1 += av1.x * bcol[4 * r4] + av1.y * bcol[4 * r4 + 1] +
              av1.z * bcol[4 * r4 + 2] + av1.w * bcol[4 * r4 + 3];
    }
    out8[2 * d] = f2b(w0 + acc0);
    out8[2 * d + 1] = f2b(w1 + acc1);
  }
  *(short8*)(wb + e0) = out8;
}

// ---------------- Kernel 2: C[m][n] = sum_k X[m][k] * W'[n][k] ---------------
// R2 config (128x128 tile, BK=64, 2x2 waves of 64x64, 4x4 frags) + two fixes:
//  (a) staging addresses hoisted: per-lane offset vA/vB is k-invariant; the
//      it*32*K and k0 terms are wave-uniform -> scalar pipe, minimal loop VALU.
//  (b) XCD-aware block swizzle: each XCD owns an 11-wide column strip and walks
//      32 rows with fixed n-tile -> B tile (512 KB) stays L2-resident.
// XOR swizzle: chunk c of row r lives at slot (c ^ (r&7)) -> 0 bank conflicts.
__global__ __launch_bounds__(256) void gemm_kernel(const short* __restrict__ xb,
                                                   const short* __restrict__ wb,
                                                   float* __restrict__ out) {
  __shared__ __align__(16) short As[128 * 64];  // 16 KB
  __shared__ __align__(16) short Bs[128 * 64];  // 16 KB

  const int tid = threadIdx.x;
  const int wave = tid >> 6, lane = tid & 63;
  const int wm = wave >> 1, wn = wave & 1;      // 2x2 wave grid, 64x64 each
  const int l15 = lane & 15, quad = lane >> 4;

  // --- XCD swizzle: 44 n-tiles = 4 strips x 11; 64 m-tiles = 2 halves x 32.
  // xcd = bid&7 (dispatch heuristic): strip = xcd&3, half = xcd>>2.
  // Within (strip,half): t = bid>>3, n-tile changes every 32 blocks.
  int bid = blockIdx.x;
  int t = bid >> 3;
  int strip = bid & 3, half = (bid >> 2) & 1;
  int xt = strip * 11 + (t >> 5);               // 0..43
  int yt = half * 32 + (t & 31);                // 0..63
  const int m0 = yt * 128, n0 = xt * 128;

  const short* a_base = xb + (size_t)m0 * K_DIM;
  const short* b_base = wb + (size_t)n0 * K_DIM;

  // Per-lane k-invariant staging offset (shorts). For staging op `it`:
  //   gi = it*256 + tid, row = it*32 + (tid>>3), slot = tid&7,
  //   chunk = slot ^ (row&7) = (tid&7) ^ ((tid>>3)&7)   (it*32 ≡ 0 mod 8)
  const unsigned r0 = tid >> 3;                           // 0..31
  const unsigned cc = ((tid & 7) ^ (r0 & 7)) * 8;         // chunk off (shorts)
  const unsigned vOff = r0 * K_DIM + cc;                  // per-lane invariant

  f32x4 acc[4][4] = {};

  // Swizzled, k0-invariant LDS read offsets (shorts).
  int a_off[2][4], b_off[2][4];
#pragma unroll
  for (int ks = 0; ks < 2; ++ks) {
    int c = ks * 4 + quad;                       // chunk index 0..7
#pragma unroll
    for (int i = 0; i < 4; ++i) {
      int ra = wm * 64 + i * 16 + l15;
      int rb = wn * 64 + i * 16 + l15;
      a_off[ks][i] = (ra * 8 + (c ^ (ra & 7))) * 8;
      b_off[ks][i] = (rb * 8 + (c ^ (rb & 7))) * 8;
    }
  }

  for (int k0 = 0; k0 < K_DIM; k0 += 64) {
    __syncthreads();  // previous tile's LDS reads done before overwrite
#pragma unroll
    for (int it = 0; it < 4; ++it) {
      // uniform part: it*32*K + k0 (scalar); per-lane part: vOff (VGPR)
      async16(&As[it * 2048 + tid * 8],
              a_base + (size_t)(it * 32 * K_DIM + k0) + vOff);
      async16(&Bs[it * 2048 + tid * 8],
              b_base + (size_t)(it * 32 * K_DIM + k0) + vOff);
    }
    __syncthreads();  // vmcnt(0) drain -> LDS ready

#pragma unroll
    for (int ks = 0; ks < 2; ++ks) {
      short8 af[4], bf[4];
#pragma unroll
      for (int mi = 0; mi < 4; ++mi) af[mi] = *(const short8*)&As[a_off[ks][mi]];
#pragma unroll
      for (int ni = 0; ni < 4; ++ni) bf[ni] = *(const short8*)&Bs[b_off[ks][ni]];
#pragma unroll
      for (int mi = 0; mi < 4; ++mi)
#pragma unroll
        for (int ni = 0; ni < 4; ++ni)
          acc[mi][ni] = __builtin_amdgcn_mfma_f32_16x16x32_bf16(
              af[mi], bf[ni], acc[mi][ni], 0, 0, 0);
    }
  }

  // Epilogue: C/D layout col = lane&15, row = quad*4 + reg  [m89-verified]
  float* op = out + (size_t)(m0 + wm * 64 + quad * 4) * N_DIM + n0 + wn * 64 + l15;
#pragma unroll
  for (int mi = 0; mi < 4; ++mi)
#pragma unroll
    for (int r = 0; r < 4; ++r)
#pragma unroll
      for (int ni = 0; ni < 4; ++ni)
        op[(size_t)(mi * 16 + r) * N_DIM + ni * 16] = acc[mi][ni][r];
}

// -----------------------------------------------------------------------------
extern "C" void kernel_launch(void* const* d_in, const int* in_sizes, int n_in,
                              void* d_out, int out_size, void* d_ws, size_t ws_size,
                              hipStream_t stream) {
  const float* x      = (const float*)d_in[0];  // [4,2048,2048] fp32
  const int*   packed = (const int*)d_in[1];    // [5767168] int32 (byte values)
  const float* scales = (const float*)d_in[2];  // [90112]
  const float* zeros  = (const float*)d_in[3];  // [90112]
  const float* lA     = (const float*)d_in[4];  // [2048,16]
  const float* lB     = (const float*)d_in[5];  // [16,5632]
  float* out = (float*)d_out;                   // [4,2048,5632] fp32

  short* xb = (short*)d_ws;                     // x in bf16: 16,777,216 shorts
  short* wb = xb + (size_t)M_DIM * K_DIM;       // W' in bf16: 11,534,336 shorts

  prep_kernel<<<CVT_BLOCKS + N_DIM, 256, 0, stream>>>(x, packed, scales, zeros,
                                                      lA, lB, xb, wb);
  gemm_kernel<<<(N_DIM / 128) * (M_DIM / 128), 256, 0, stream>>>(xb, wb, out);
}